// Round 12
// baseline (15.924 us; speedup 1.0000x reference)
//
#include <hip/hip_runtime.h>
#include <math.h>

#define BATCH 4
#define CH 128
#define NOSC 128
#define TK 128
#define NAUD 32768
#define NVS 129          // virtual segments: 0=head, 1..127=interior k=vs-1, 128=tail

// seg tuple (8 floats, 32B): {f0h, dfh, cRev, a0, da, pad, pad, pad}
//   rev(j) = cRev + jp1*f0h + dfh*jp1^2/512 ;  amp(j) = a0 + da*(2*jp1-1)/512

// ---------------- Stage 1: dots + phase scan -> per-segment tuples ----------------
// One block per (b,o); 512 threads = 128 knots x 4 channel-groups of 32.
__global__ __launch_bounds__(512) void osc1_kernel(
    const float* __restrict__ x, const float* __restrict__ W,
    const float* __restrict__ bvec, const float* __restrict__ baselines,
    float* __restrict__ seg)
{
    const int blk = blockIdx.x;
    const int b = blk >> 7, o = blk & 127;
    const int tid = threadIdx.x;
    const int k = tid & 127;
    // wave-uniform channel-group base -> W reads become scalar s_loads
    const int c0 = __builtin_amdgcn_readfirstlane(tid >> 7) * 32;

    const float* __restrict__ Wr = W + (2*o)*CH;   // uniform addresses
    const float* __restrict__ Wi = Wr + CH;
    const float* xb = x + b*CH*TK + k;

    // 32 channels per thread, one fully-in-flight load batch
    float re = 0.f, im = 0.f;
    {
        float xv[32];
        #pragma unroll
        for (int u = 0; u < 32; ++u) xv[u] = xb[(c0+u)*TK];
        #pragma unroll
        for (int u = 0; u < 32; ++u) { re = fmaf(xv[u], Wr[c0+u], re); im = fmaf(xv[u], Wi[c0+u], im); }
    }

    __shared__ float sRe[512], sIm[512];
    sRe[tid] = re; sIm[tid] = im;
    __syncthreads();

    __shared__ float fsh[TK], ash[TK];
    __shared__ double wtot;
    float fr = 0.f, amp = 0.f;
    if (tid < 128) {
        float rr = sRe[tid] + sRe[tid+128] + sRe[tid+256] + sRe[tid+384] + bvec[2*o];
        float ii = sIm[tid] + sIm[tid+128] + sIm[tid+256] + sIm[tid+384] + bvec[2*o+1];
        rr = fmaf(rr, 0.01f, baselines[2*o]);
        ii = fmaf(ii, 0.01f, baselines[2*o+1]);
        const float BASEF  = 40.0f/11025.0f;
        const float RANGEF = 8960.0f/11025.0f;
        amp = fmaf(fmaf(rr, rr, ii*ii), RANGEF, BASEF);
        float th = atan2f(ii, rr) * (1.0f/3.14159265358979323846f);
        fr = th*th;
        fsh[k] = fr; ash[k] = amp;
    }
    __syncthreads();

    double ev = 0.0;
    if (tid < 128) {
        // segment freq-sum scan (f64), closed form per 256-sample segment
        ev = (k == 0) ? 128.0*(double)fr
                      : 128.0*((double)fsh[k-1] + (double)fr);
        const int lane = tid & 63;
        #pragma unroll
        for (int d = 1; d < 64; d <<= 1) {
            double up = __shfl_up(ev, d);
            if (lane >= d) ev += up;
        }
        if (tid == 63) wtot = ev;
    }
    __syncthreads();
    if (tid < 128) {
        if (tid >= 64) ev += wtot;
        double xrev = ev * 0.5;                    // phase base in revolutions
        float cRev = (float)(xrev - floor(xrev)); // mod 1 rev, f64 once

        float* base = seg + ((size_t)(b*NVS)*NOSC + o)*8;
        const int vs = k + 1;   // interior k<=126; tail vs=128 from k==127
        float f0h = 0.5f*fr;
        float dfh = (k <= 126) ? 0.5f*(fsh[k+1] - fr) : 0.0f;
        float da  = (k <= 126) ? (ash[k+1] - amp) : 0.0f;
        float* p = base + (size_t)vs*NOSC*8;
        *(float4*)p = make_float4(f0h, dfh, cRev, amp);
        p[4] = da;
        if (k == 0) {   // head vs=0: clamped to knot 0, phase base 0
            *(float4*)base = make_float4(f0h, 0.0f, 0.0f, amp);
            base[4] = 0.0f;
        }
    }
}

// ---------------- Stage 2: scalar-load synthesize, no LDS staging ----------------
// One block per (b, z). 512 thr = 8 waves; wave w = osc group w (16 osc);
// lane = sample slot (64); 4 samples per lane (slots l, l+64, l+128, l+192).
// Tuple addresses are wave-uniform -> s_load into SGPRs (no vmem in loop).
__global__ __launch_bounds__(512) void osc2_kernel(
    const float* __restrict__ seg, float* __restrict__ out)
{
    const int blk = blockIdx.x;
    const int b   = blk >> 7;
    const int z   = blk & 127;
    const int tid = threadIdx.x;
    const int l   = tid & 63;                                   // lane / sample slot
    const int w   = __builtin_amdgcn_readfirstlane(tid >> 6);   // wave id (uniform)

    __shared__ float red[8][256];

    float acc[4] = {0.f, 0.f, 0.f, 0.f};

    if (z != 0) {
        // interior: slots 0..255, jint = slot+1, uniform vs=z
        const float* __restrict__ p = seg + ((size_t)(b*NVS + z)*NOSC + w*16)*8;
        float jp1_[4], jsq_[4], ww_[4];
        #pragma unroll
        for (int m = 0; m < 4; ++m) {
            float jp1 = (float)(64*m + l + 1);
            jp1_[m] = jp1;
            jsq_[m] = jp1*jp1*(1.0f/512.0f);
            ww_[m]  = (2.0f*jp1 - 1.0f)*(1.0f/512.0f);
        }
        #pragma unroll
        for (int i = 0; i < 16; ++i) {
            const float f0h = p[i*8+0], dfh = p[i*8+1], cR = p[i*8+2];
            const float a0  = p[i*8+3], da  = p[i*8+4];
            #pragma unroll
            for (int m = 0; m < 4; ++m) {
                float rev = fmaf(dfh, jsq_[m], fmaf(jp1_[m], f0h, cR));
                float fr_, sn;
                asm("v_fract_f32 %0, %1" : "=v"(fr_) : "v"(rev));   // rev mod 1
                asm("v_sin_f32 %0, %1"   : "=v"(sn)  : "v"(fr_));   // sin(2*pi*frac)
                acc[m] = fmaf(fmaf(da, ww_[m], a0), sn, acc[m]);
            }
        }
    } else {
        // z==0: slots 0..127 = head (vs=0, jint=slot+1, t=slot);
        //       slots 128..255 = tail (vs=128, jint=slot-127, t=NAUD-256+slot)
        const float* __restrict__ pH = seg + ((size_t)(b*NVS +   0)*NOSC + w*16)*8;
        const float* __restrict__ pT = seg + ((size_t)(b*NVS + 128)*NOSC + w*16)*8;
        float jp1_[2], jsq_[2], ww_[2];
        #pragma unroll
        for (int m = 0; m < 2; ++m) {
            float jp1 = (float)(64*m + l + 1);
            jp1_[m] = jp1;
            jsq_[m] = jp1*jp1*(1.0f/512.0f);
            ww_[m]  = (2.0f*jp1 - 1.0f)*(1.0f/512.0f);
        }
        #pragma unroll
        for (int i = 0; i < 16; ++i) {
            const float f0hH = pH[i*8+0], cRH = pH[i*8+2], a0H = pH[i*8+3];
            const float f0hT = pT[i*8+0], cRT = pT[i*8+2], a0T = pT[i*8+3];
            #pragma unroll
            for (int m = 0; m < 2; ++m) {
                float fr_, sn;
                // head: dfh=0, da=0, cRev=0 by construction, but use stored vals
                float revH = fmaf(jp1_[m], f0hH, cRH);
                asm("v_fract_f32 %0, %1" : "=v"(fr_) : "v"(revH));
                asm("v_sin_f32 %0, %1"   : "=v"(sn)  : "v"(fr_));
                acc[m] = fmaf(a0H, sn, acc[m]);
                float revT = fmaf(jp1_[m], f0hT, cRT);
                asm("v_fract_f32 %0, %1" : "=v"(fr_) : "v"(revT));
                asm("v_sin_f32 %0, %1"   : "=v"(sn)  : "v"(fr_));
                acc[2+m] = fmaf(a0T, sn, acc[2+m]);
            }
        }
    }

    #pragma unroll
    for (int m = 0; m < 4; ++m)
        red[w][64*m + l] = acc[m];
    __syncthreads();

    if (tid < 256) {
        float v = 0.f;
        #pragma unroll
        for (int gg = 0; gg < 8; ++gg) v += red[gg][tid];
        int t = (z != 0) ? ((2*z - 1)*128 + tid)
                         : ((tid < 128) ? tid : (NAUD - 256 + tid));
        out[b*NAUD + t] = v;
    }
}

extern "C" void kernel_launch(void* const* d_in, const int* in_sizes, int n_in,
                              void* d_out, int out_size, void* d_ws, size_t ws_size,
                              hipStream_t stream)
{
    const float* x         = (const float*)d_in[0];
    const float* W         = (const float*)d_in[1];
    const float* bvec      = (const float*)d_in[2];
    const float* baselines = (const float*)d_in[3];
    float* out = (float*)d_out;
    float* seg = (float*)d_ws;   // 4*129*128*8*4B = 2.11 MiB

    osc1_kernel<<<BATCH*NOSC, 512, 0, stream>>>(x, W, bvec, baselines, seg);
    osc2_kernel<<<BATCH*128, 512, 0, stream>>>(seg, out);
}

// Round 13
// 15.013 us; speedup vs baseline: 1.0607x; 1.0607x over previous
//
#include <hip/hip_runtime.h>
#include <math.h>

#define BATCH 4
#define CH 128
#define NOSC 128
#define TK 128
#define NAUD 32768
#define NVS 129          // virtual segments: 0=head, 1..127=interior k=vs-1, 128=tail

// seg tuple (8 floats, 32B): {f0h, dfh, cRev, a0, da, pad, pad, pad}
//   rev(j) = cRev + jp1*f0h + dfh*jp1^2/512 ;  amp(j) = a0 + da*(2*jp1-1)/512

// ---------------- Stage 1: dots + phase scan -> per-segment tuples ----------------
// One block per (b,o); 512 threads = 128 knots x 4 channel-groups of 32.
__global__ __launch_bounds__(512) void osc1_kernel(
    const float* __restrict__ x, const float* __restrict__ W,
    const float* __restrict__ bvec, const float* __restrict__ baselines,
    float* __restrict__ seg)
{
    const int blk = blockIdx.x;
    const int b = blk >> 7, o = blk & 127;
    const int tid = threadIdx.x;
    const int k = tid & 127;
    // wave-uniform channel-group base -> W reads become scalar s_loads
    const int c0 = __builtin_amdgcn_readfirstlane(tid >> 7) * 32;

    const float* __restrict__ Wr = W + (2*o)*CH;   // uniform addresses
    const float* __restrict__ Wi = Wr + CH;
    const float* xb = x + b*CH*TK + k;

    // 32 channels per thread, one fully-in-flight load batch
    float re = 0.f, im = 0.f;
    {
        float xv[32];
        #pragma unroll
        for (int u = 0; u < 32; ++u) xv[u] = xb[(c0+u)*TK];
        #pragma unroll
        for (int u = 0; u < 32; ++u) { re = fmaf(xv[u], Wr[c0+u], re); im = fmaf(xv[u], Wi[c0+u], im); }
    }

    __shared__ float sRe[512], sIm[512];
    sRe[tid] = re; sIm[tid] = im;
    __syncthreads();

    __shared__ float fsh[TK], ash[TK];
    __shared__ double wtot;
    float fr = 0.f, amp = 0.f;
    if (tid < 128) {
        float rr = sRe[tid] + sRe[tid+128] + sRe[tid+256] + sRe[tid+384] + bvec[2*o];
        float ii = sIm[tid] + sIm[tid+128] + sIm[tid+256] + sIm[tid+384] + bvec[2*o+1];
        rr = fmaf(rr, 0.01f, baselines[2*o]);
        ii = fmaf(ii, 0.01f, baselines[2*o+1]);
        const float BASEF  = 40.0f/11025.0f;
        const float RANGEF = 8960.0f/11025.0f;
        amp = fmaf(fmaf(rr, rr, ii*ii), RANGEF, BASEF);
        float th = atan2f(ii, rr) * (1.0f/3.14159265358979323846f);
        fr = th*th;
        fsh[k] = fr; ash[k] = amp;
    }
    __syncthreads();

    double ev = 0.0;
    if (tid < 128) {
        // segment freq-sum scan (f64), closed form per 256-sample segment
        ev = (k == 0) ? 128.0*(double)fr
                      : 128.0*((double)fsh[k-1] + (double)fr);
        const int lane = tid & 63;
        #pragma unroll
        for (int d = 1; d < 64; d <<= 1) {
            double up = __shfl_up(ev, d);
            if (lane >= d) ev += up;
        }
        if (tid == 63) wtot = ev;
    }
    __syncthreads();
    if (tid < 128) {
        if (tid >= 64) ev += wtot;
        double xrev = ev * 0.5;                    // phase base in revolutions
        float cRev = (float)(xrev - floor(xrev)); // mod 1 rev, f64 once

        float* base = seg + ((size_t)(b*NVS)*NOSC + o)*8;
        const int vs = k + 1;   // interior k<=126; tail vs=128 from k==127
        float f0h = 0.5f*fr;
        float dfh = (k <= 126) ? 0.5f*(fsh[k+1] - fr) : 0.0f;
        float da  = (k <= 126) ? (ash[k+1] - amp) : 0.0f;
        float* p = base + (size_t)vs*NOSC*8;
        *(float4*)p = make_float4(f0h, dfh, cRev, amp);
        p[4] = da;
        if (k == 0) {   // head vs=0: clamped to knot 0, phase base 0
            *(float4*)base = make_float4(f0h, 0.0f, 0.0f, amp);
            base[4] = 0.0f;
        }
    }
}

// ---------------- Stage 2: 4-samples-per-tuple-read synthesize ----------------
// One block per (b, z): z=1..127 -> interior segment (256 samples, uniform vs=z);
// z=0 -> head 128 (vs=0) + tail 128 (vs=128).
// 512 thr = 64 sample-slots x 8 osc-groups of 16. Each thread: 16 osc x 4 samples.
// One vs-slice = 128 osc x 8 floats = 256 float4 (4KB).
__global__ __launch_bounds__(512) void osc2_kernel(
    const float* __restrict__ seg, float* __restrict__ out)
{
    const int blk = blockIdx.x;
    const int b   = blk >> 7;
    const int z   = blk & 127;
    const int tid = threadIdx.x;
    const int s   = tid & 63;       // sample slot
    const int g   = tid >> 6;       // osc group (16 osc)

    __shared__ float4 tupA[256];
    __shared__ float4 tupB[256];    // only used by z==0 (tail)
    __shared__ float  red[8][256];

    const float4* srcA = (const float4*)(seg + ((size_t)(b*NVS) + (z == 0 ? 0 : z))*NOSC*8);
    if (z == 0) {
        const float4* srcB = (const float4*)(seg + ((size_t)(b*NVS) + 128)*NOSC*8);
        if (tid < 256) tupA[tid]       = srcA[tid];
        else           tupB[tid - 256] = srcB[tid - 256];
    } else {
        if (tid < 256) tupA[tid] = srcA[tid];
    }
    __syncthreads();

    float acc0 = 0.f, acc1 = 0.f, acc2 = 0.f, acc3 = 0.f;
    const float* bpA = (const float*)&tupA[g*32];   // group's 16 tuples
    const float* bpB = (const float*)&tupB[g*32];

    if (z != 0) {
        float jp1_[4], jsq_[4], w_[4];
        #pragma unroll
        for (int m = 0; m < 4; ++m) {
            float jp1 = (float)(64*m + s + 1);
            jp1_[m] = jp1;
            jsq_[m] = jp1*jp1*(1.0f/512.0f);
            w_[m]   = (2.0f*jp1 - 1.0f)*(1.0f/512.0f);
        }
        #pragma unroll
        for (int i = 0; i < 16; ++i) {
            float4 v = *(const float4*)(bpA + i*8);
            float da = bpA[i*8 + 4];
            float fr_, sn;
            float rev0 = fmaf(v.y, jsq_[0], fmaf(jp1_[0], v.x, v.z));
            asm("v_fract_f32 %0, %1" : "=v"(fr_) : "v"(rev0));
            asm("v_sin_f32 %0, %1"   : "=v"(sn)  : "v"(fr_));
            acc0 = fmaf(fmaf(da, w_[0], v.w), sn, acc0);
            float rev1 = fmaf(v.y, jsq_[1], fmaf(jp1_[1], v.x, v.z));
            asm("v_fract_f32 %0, %1" : "=v"(fr_) : "v"(rev1));
            asm("v_sin_f32 %0, %1"   : "=v"(sn)  : "v"(fr_));
            acc1 = fmaf(fmaf(da, w_[1], v.w), sn, acc1);
            float rev2 = fmaf(v.y, jsq_[2], fmaf(jp1_[2], v.x, v.z));
            asm("v_fract_f32 %0, %1" : "=v"(fr_) : "v"(rev2));
            asm("v_sin_f32 %0, %1"   : "=v"(sn)  : "v"(fr_));
            acc2 = fmaf(fmaf(da, w_[2], v.w), sn, acc2);
            float rev3 = fmaf(v.y, jsq_[3], fmaf(jp1_[3], v.x, v.z));
            asm("v_fract_f32 %0, %1" : "=v"(fr_) : "v"(rev3));
            asm("v_sin_f32 %0, %1"   : "=v"(sn)  : "v"(fr_));
            acc3 = fmaf(fmaf(da, w_[3], v.w), sn, acc3);
        }
    } else {
        float jp1_[2], jsq_[2], w_[2];
        #pragma unroll
        for (int m = 0; m < 2; ++m) {
            float jp1 = (float)(64*m + s + 1);
            jp1_[m] = jp1;
            jsq_[m] = jp1*jp1*(1.0f/512.0f);
            w_[m]   = (2.0f*jp1 - 1.0f)*(1.0f/512.0f);
        }
        #pragma unroll
        for (int i = 0; i < 16; ++i) {
            float4 vA = *(const float4*)(bpA + i*8);
            float daA = bpA[i*8 + 4];
            float4 vB = *(const float4*)(bpB + i*8);
            float daB = bpB[i*8 + 4];
            float fr_, sn;
            float rev0 = fmaf(vA.y, jsq_[0], fmaf(jp1_[0], vA.x, vA.z));
            asm("v_fract_f32 %0, %1" : "=v"(fr_) : "v"(rev0));
            asm("v_sin_f32 %0, %1"   : "=v"(sn)  : "v"(fr_));
            acc0 = fmaf(fmaf(daA, w_[0], vA.w), sn, acc0);
            float rev1 = fmaf(vA.y, jsq_[1], fmaf(jp1_[1], vA.x, vA.z));
            asm("v_fract_f32 %0, %1" : "=v"(fr_) : "v"(rev1));
            asm("v_sin_f32 %0, %1"   : "=v"(sn)  : "v"(fr_));
            acc1 = fmaf(fmaf(daA, w_[1], vA.w), sn, acc1);
            float rev2 = fmaf(vB.y, jsq_[0], fmaf(jp1_[0], vB.x, vB.z));
            asm("v_fract_f32 %0, %1" : "=v"(fr_) : "v"(rev2));
            asm("v_sin_f32 %0, %1"   : "=v"(sn)  : "v"(fr_));
            acc2 = fmaf(fmaf(daB, w_[0], vB.w), sn, acc2);
            float rev3 = fmaf(vB.y, jsq_[1], fmaf(jp1_[1], vB.x, vB.z));
            asm("v_fract_f32 %0, %1" : "=v"(fr_) : "v"(rev3));
            asm("v_sin_f32 %0, %1"   : "=v"(sn)  : "v"(fr_));
            acc3 = fmaf(fmaf(daB, w_[1], vB.w), sn, acc3);
        }
    }

    red[g][      s] = acc0;
    red[g][ 64 + s] = acc1;
    red[g][128 + s] = acc2;
    red[g][192 + s] = acc3;
    __syncthreads();

    if (tid < 256) {
        float v = 0.f;
        #pragma unroll
        for (int gg = 0; gg < 8; ++gg) v += red[gg][tid];
        int t = (z != 0) ? ((2*z - 1)*128 + tid)
                         : ((tid < 128) ? tid : (NAUD - 256 + tid));
        out[b*NAUD + t] = v;
    }
}

extern "C" void kernel_launch(void* const* d_in, const int* in_sizes, int n_in,
                              void* d_out, int out_size, void* d_ws, size_t ws_size,
                              hipStream_t stream)
{
    const float* x         = (const float*)d_in[0];
    const float* W         = (const float*)d_in[1];
    const float* bvec      = (const float*)d_in[2];
    const float* baselines = (const float*)d_in[3];
    float* out = (float*)d_out;
    float* seg = (float*)d_ws;   // 4*129*128*8*4B = 2.11 MiB

    osc1_kernel<<<BATCH*NOSC, 512, 0, stream>>>(x, W, bvec, baselines, seg);
    osc2_kernel<<<BATCH*128, 512, 0, stream>>>(seg, out);
}